// Round 4
// baseline (211.767 us; speedup 1.0000x reference)
//
#include <hip/hip_runtime.h>
#include <hip/hip_bf16.h>

typedef __hip_bfloat16 bf16;
typedef short short8 __attribute__((ext_vector_type(8)));
typedef float f32x4 __attribute__((ext_vector_type(4)));
typedef unsigned int u32x4 __attribute__((ext_vector_type(4)));

#define C_   128
#define N_   4096
#define NH_  8
#define HD_  16
#define FF_  2048
#define SCALE_Q 0.360673760222241f   // 0.25 * log2(e); attn uses v_exp_f32 (2^x)

__device__ __forceinline__ unsigned short f2bf_bits(float f) {
    bf16 h = __float2bfloat16(f);
    return *reinterpret_cast<unsigned short*>(&h);
}
// truncation-mode bf16 pack: single v_perm_b32. Bit-identical to (hi&0xffff0000)|(lo>>16).
__device__ __forceinline__ unsigned int pack_trunc(float lo, float hi) {
    return __builtin_amdgcn_perm(__float_as_uint(hi), __float_as_uint(lo), 0x07060302u);
}
__device__ __forceinline__ short f2bf_trunc(float f) {
    return (short)(__float_as_uint(f) >> 16);
}
__device__ __forceinline__ float bfs2f(short s) {
    return __uint_as_float(((unsigned int)(unsigned short)s) << 16);
}
__device__ __forceinline__ float fast_exp2(float x) {
    return __builtin_amdgcn_exp2f(x);
}
__device__ __forceinline__ f32x4 mfma16(short8 a, short8 b, f32x4 c) {
    return __builtin_amdgcn_mfma_f32_16x16x32_bf16(a, b, c, 0, 0, 0);
}

// Grid-wide barrier: monotonic phase counter, agent-scope (cross-XCD safe).
// Safe because grid(256) <= co-resident capacity (LDS 80KB -> >=1 blk/CU x 256 CU).
__device__ __forceinline__ void grid_sync(unsigned int* bar, unsigned int target) {
    __syncthreads();
    if (threadIdx.x == 0) {
        __hip_atomic_fetch_add(bar, 1u, __ATOMIC_ACQ_REL, __HIP_MEMORY_SCOPE_AGENT);
        while (__hip_atomic_load(bar, __ATOMIC_ACQUIRE, __HIP_MEMORY_SCOPE_AGENT) < target)
            __builtin_amdgcn_s_sleep(2);
    }
    __syncthreads();
}

// =================== FUSED: prep + qkv + attn + mega, 256 blocks x 512 threads ==========
// R15: single persistent kernel, 3 grid_syncs. Stage work mapping:
//   S0: xT-transpose (65536 jobs) + QKV/Wo weight prep (8192 jobs)   [1 job/thread]
//   S1: qkv GEMM (6144 wave-jobs over 2048 waves = 3/wave) + W1/W2 prep (65536 jobs)
//       (W-prep only needed by S3 -> folded here to overlap qkv's idle mem pipe)
//   S2: attn, 512 jobs = 2 half-block jobs (4 waves each) per block
//   S3: mega, 1 row-tile per block (identical to R13/R14 k_mega body)
// All per-stage math verbatim from R14 -> bit-identical outputs.
__global__ void __launch_bounds__(512)
k_fused(const float* __restrict__ x,
        const float* __restrict__ Wq, const float* __restrict__ Wk,
        const float* __restrict__ Wv, const float* __restrict__ Wo,
        const float* __restrict__ W1, const float* __restrict__ W2,
        const float* __restrict__ bq, const float* __restrict__ bk,
        const float* __restrict__ bv, const float* __restrict__ bo,
        const float* __restrict__ b1, const float* __restrict__ b2,
        const float* __restrict__ g1, const float* __restrict__ be1,
        const float* __restrict__ g2, const float* __restrict__ be2,
        bf16* __restrict__ xTf, bf16* __restrict__ Wqkvf, bf16* __restrict__ Wof,
        bf16* __restrict__ W1f, bf16* __restrict__ W2f,
        bf16* __restrict__ qf, bf16* __restrict__ kf, bf16* __restrict__ vf,
        bf16* __restrict__ af,
        float* __restrict__ out, unsigned int* __restrict__ bar)
{
    __shared__ __align__(16) union {
        unsigned int P[2][4][4][2][320];     // attn: [half][w4][qt][dbuf], 80 KB
        float comba[2][4][4][64][8];         // attn epilogue: [half][qt][w4][lane], 64 KB
        struct {
            unsigned int Pb[8][2][320];      // mega transpose dbuf, 20 KB
            float comb[224][64];             // mega ffn2 partials, 56 KB
        } mg;
    } sh;

    const int tid  = threadIdx.x, wave = tid >> 6, lane = tid & 63;
    const int col  = lane & 15,  quad = lane >> 4;
    const int blk  = blockIdx.x;                 // [0,256)
    const f32x4 zero = {};

    // ======================= STAGE 0: xT transpose + QKV/Wo weight prep ==================
    {
        const int i = blk * 512 + tid;           // [0, 131072)
        if (i < 8192) {                          // QKV (o 0..383) + Wo (o 384..511), K=128
            const int o = i >> 4;
            const int kblk = (i >> 2) & 3, g = i & 3;
            const int odx = (o < 384) ? o : o - 384;
            const float* row = (o < 128) ? (Wq + o * 128)
                             : (o < 256) ? (Wk + (o - 128) * 128)
                             : (o < 384) ? (Wv + (o - 256) * 128)
                                         : (Wo + (o - 384) * 128);
            bf16* buf = (o < 384) ? Wqkvf : Wof;
            bf16* dst = buf + ((((odx >> 4) << 2) + kblk) * 512 + ((g << 4) + (odx & 15)) * 8);
            const int k0 = kblk * 32 + g * 4;
            const f32x4 lo = *(const f32x4*)(row + k0);
            const f32x4 hi = *(const f32x4*)(row + k0 + 16);
            u32x4 w;
            #pragma unroll
            for (int j = 0; j < 4; ++j)
                w[j] = ((unsigned int)f2bf_bits(hi[j]) << 16) | f2bf_bits(lo[j]);
            *(u32x4*)dst = w;
        } else if (i < 73728) {                  // x : [128][4096] -> xTf A-frags
            const int t = i - 8192;              // [0, 65536)
            const int n = t & 4095, g = (t >> 12) & 3, cblk = t >> 14;
            const int c0 = cblk * 32 + g * 4;
            const float* xs = x + (size_t)c0 * 4096 + n;
            u32x4 w;
            #pragma unroll
            for (int j = 0; j < 4; ++j)
                w[j] = ((unsigned int)f2bf_bits(xs[(size_t)(16 + j) * 4096]) << 16)
                     | f2bf_bits(xs[(size_t)j * 4096]);
            bf16* dst = xTf + ((((n >> 4) << 2) + cblk) * 512 + ((g << 4) + (n & 15)) * 8);
            *(u32x4*)dst = w;
        }
    }

    grid_sync(bar, 256);

    // ======================= STAGE 1: QKV GEMM + W1/W2 prep ==============================
    {
        const int wv = blk * 8 + wave;           // [0, 2048)
        #pragma unroll
        for (int j = 0; j < 3; ++j) {
            const int gw = j * 2048 + wv;        // [0, 6144)
            const int rt = gw / 24, ct = gw % 24;
            f32x4 acc = {};
            #pragma unroll
            for (int c = 0; c < 4; ++c) {
                short8 a = *(const short8*)(xTf + ((size_t)(rt * 4 + c) << 9) + lane * 8);
                short8 b = *(const short8*)(Wqkvf + ((size_t)(ct * 4 + c) << 9) + lane * 8);
                acc = mfma16(a, b, acc);
            }
            #pragma unroll
            for (int r = 0; r < 4; ++r) {
                const int m = rt * 16 + quad * 4 + r;
                const int n = ct * 16 + col;
                const float v = acc[r];
                if (n < 128) {
                    const int h = n >> 4, ch = n & 15;
                    qf[((h << 8) + (m >> 4)) * 256 + (((ch >> 3) << 4) + (m & 15)) * 8 + (ch & 7)] =
                        __float2bfloat16((v + bq[n]) * SCALE_Q);
                } else if (n < 256) {
                    const int c2 = n - 128, h = c2 >> 4, ch = c2 & 15;
                    kf[((h << 8) + (m >> 4)) * 256 + (((ch >> 3) << 4) + (m & 15)) * 8 + (ch & 7)] =
                        __float2bfloat16(v + bk[c2]);
                } else {
                    const int c2 = n - 256, h = c2 >> 4, ch = c2 & 15;
                    const int ko = m & 31;
                    const int pos = ((ko & 15) << 1) + (ko >> 4);
                    vf[((h << 7) + (m >> 5)) * 512 + (((pos >> 3) << 4) + ch) * 8 + (pos & 7)] =
                        __float2bfloat16(v + bv[c2]);
                }
            }
        }
        // ---- W1/W2 prep (needed only by stage 3) ----
        const int i = blk * 512 + tid;           // [0, 131072)
        if (i < 65536) {
            const float* row;
            bf16* dst;
            int kblk, g;
            if (i < 32768) {                     // W1 : [2048][128]
                const int o = i >> 4;
                kblk = (i >> 2) & 3; g = i & 3;
                row = W1 + o * 128;
                dst = W1f + ((((o >> 4) << 2) + kblk) * 512 + ((g << 4) + (o & 15)) * 8);
            } else {                             // W2 : [128][2048]
                const int t = i - 32768, o = t >> 8;
                kblk = (t >> 2) & 63; g = t & 3;
                row = W2 + o * 2048;
                dst = W2f + ((((o >> 4) << 6) + kblk) * 512 + ((g << 4) + (o & 15)) * 8);
            }
            const int k0 = kblk * 32 + g * 4;
            const f32x4 lo = *(const f32x4*)(row + k0);
            const f32x4 hi = *(const f32x4*)(row + k0 + 16);
            u32x4 w;
            #pragma unroll
            for (int j = 0; j < 4; ++j)
                w[j] = ((unsigned int)f2bf_bits(hi[j]) << 16) | f2bf_bits(lo[j]);
            *(u32x4*)dst = w;
        }
    }

    grid_sync(bar, 512);

    // ======================= STAGE 2: attention (2 half-block jobs) ======================
    {
        const int half = wave >> 2, w4 = wave & 3;
        const int job  = blk * 2 + half;         // [0, 512)
        const int h    = job >> 6;
        const int tile0 = (job & 63) << 2;

        short8 aq[4] = {{}, {}, {}, {}};
        if (quad < 2) {
            #pragma unroll
            for (int qt = 0; qt < 4; ++qt)
                aq[qt] = *(const short8*)(qf + ((size_t)((h << 8) + tile0 + qt) << 8) + lane * 8);
        }

        const short8 onesb = { (short)0x3F80, (short)0x3F80, (short)0x3F80, (short)0x3F80,
                               (short)0x3F80, (short)0x3F80, (short)0x3F80, (short)0x3F80 };

        f32x4 accO[4] = {{}, {}, {}, {}};
        f32x4 accL[4] = {{}, {}, {}, {}};

        const int kbeg = w4 << 10;

        for (int i = 0; i < 32; i += 2) {
            const int mA = kbeg + (i << 5);
            const int mB = mA + 32;

            short8 bkA0 = {}, bkA1 = {}, bkB0 = {}, bkB1 = {};
            if (quad < 2) {
                const bf16* ka = kf + ((size_t)((h << 8) + (mA >> 4)) << 8) + lane * 8;
                bkA0 = *(const short8*)(ka);
                bkA1 = *(const short8*)(ka + 256);
                bkB0 = *(const short8*)(ka + 512);
                bkB1 = *(const short8*)(ka + 768);
            }
            const short8 vA = *(const short8*)(vf + ((size_t)((h << 7) + (mA >> 5)) << 9) + lane * 8);
            const short8 vB = *(const short8*)(vf + ((size_t)((h << 7) + (mB >> 5)) << 9) + lane * 8);

            #pragma unroll
            for (int qt = 0; qt < 4; ++qt) {
                f32x4 s0 = mfma16(aq[qt], bkA0, zero);
                f32x4 s1 = mfma16(aq[qt], bkA1, zero);
                f32x4 s2 = mfma16(aq[qt], bkB0, zero);
                f32x4 s3 = mfma16(aq[qt], bkB1, zero);
                unsigned int* P0 = &sh.P[half][w4][qt][0][0];
                unsigned int* P1 = &sh.P[half][w4][qt][1][0];
                #pragma unroll
                for (int r = 0; r < 4; ++r) {
                    P0[(quad * 4 + r) * 20 + col] = pack_trunc(fast_exp2(s0[r]), fast_exp2(s1[r]));
                    P1[(quad * 4 + r) * 20 + col] = pack_trunc(fast_exp2(s2[r]), fast_exp2(s3[r]));
                }
            }
            #pragma unroll
            for (int qt = 0; qt < 4; ++qt) {
                const short* Ps0 = (const short*)&sh.P[half][w4][qt][0][0];
                const short* Ps1 = (const short*)&sh.P[half][w4][qt][1][0];
                short8 ap0 = *(const short8*)(Ps0 + col * 40 + quad * 8);
                accO[qt] = mfma16(ap0, vA, accO[qt]);
                accL[qt] = mfma16(ap0, onesb, accL[qt]);
                short8 ap1 = *(const short8*)(Ps1 + col * 40 + quad * 8);
                accO[qt] = mfma16(ap1, vB, accO[qt]);
                accL[qt] = mfma16(ap1, onesb, accL[qt]);
            }
        }

        __syncthreads();
        #pragma unroll
        for (int qt = 0; qt < 4; ++qt)
            #pragma unroll
            for (int r = 0; r < 4; ++r) {
                sh.comba[half][qt][w4][lane][r]     = accO[qt][r];
                sh.comba[half][qt][w4][lane][4 + r] = accL[qt][r];
            }
        __syncthreads();

        {   // wave w4 finalizes q-tile w4 of its half's job
            const int qt = w4, tile = tile0 + qt;
            #pragma unroll
            for (int r = 0; r < 4; ++r) {
                float O = sh.comba[half][qt][0][lane][r] + sh.comba[half][qt][1][lane][r]
                        + sh.comba[half][qt][2][lane][r] + sh.comba[half][qt][3][lane][r];
                float l = sh.comba[half][qt][0][lane][4+r] + sh.comba[half][qt][1][lane][4+r]
                        + sh.comba[half][qt][2][lane][4+r] + sh.comba[half][qt][3][lane][4+r];
                const int row16 = quad * 4 + r;
                const int pk = (col << 1) + (h & 1);
                af[((tile << 2) + (h >> 1)) * 512 + (((pk >> 3) << 4) + row16) * 8 + (pk & 7)] =
                    __float2bfloat16(O / l);
            }
        }
    }

    grid_sync(bar, 768);

    // ======================= STAGE 3: mega (oproj+LN1+FFN+LN2), rt = blk =================
    {
        const int rt = blk, n0 = rt << 4;

        short8 ao[4], xt[4];
        #pragma unroll
        for (int c = 0; c < 4; ++c) {
            ao[c] = *(const short8*)(af  + ((size_t)(rt * 4 + c) << 9) + lane * 8);
            xt[c] = *(const short8*)(xTf + ((size_t)(rt * 4 + c) << 9) + lane * 8);
        }
        f32x4 d[8];
        #pragma unroll
        for (int t = 0; t < 8; ++t) d[t] = zero;
        #pragma unroll
        for (int t = 0; t < 8; ++t)
            #pragma unroll
            for (int c = 0; c < 4; ++c) {
                short8 b = *(const short8*)(Wof + ((size_t)(t * 4 + c) << 9) + lane * 8);
                d[t] = mfma16(ao[c], b, d[t]);
            }
        #pragma unroll
        for (int t = 0; t < 8; ++t) {
            const float bt = bo[t * 16 + col];
            #pragma unroll
            for (int r = 0; r < 4; ++r) d[t][r] += bt;
        }

        float x1f[4][8];
        #pragma unroll
        for (int c = 0; c < 4; ++c) {
            unsigned int* Pw = &sh.mg.Pb[wave][c & 1][0];
            const short* Ps = (const short*)Pw;
            #pragma unroll
            for (int r = 0; r < 4; ++r)
                Pw[(quad * 4 + r) * 20 + col] = pack_trunc(d[2 * c][r], d[2 * c + 1][r]);
            short8 ar = *(const short8*)(Ps + col * 40 + quad * 8);
            #pragma unroll
            for (int j = 0; j < 8; ++j)
                x1f[c][j] = bfs2f(ar[j]) + bfs2f(xt[c][j]);
        }

        float s = 0.f, ss = 0.f;
        #pragma unroll
        for (int c = 0; c < 4; ++c)
            #pragma unroll
            for (int j = 0; j < 8; ++j) { s += x1f[c][j]; ss += x1f[c][j] * x1f[c][j]; }
        s  += __shfl_xor(s, 16);  s  += __shfl_xor(s, 32);
        ss += __shfl_xor(ss, 16); ss += __shfl_xor(ss, 32);
        const float m1 = s * (1.f / 128.f);
        const float rstd1 = rsqrtf(ss * (1.f / 128.f) - m1 * m1 + 1e-5f);
        short8 aq1[4];
        #pragma unroll
        for (int c = 0; c < 4; ++c)
            #pragma unroll
            for (int j = 0; j < 8; ++j) {
                const int pos = quad * 8 + j;
                const int ko = ((pos & 1) << 4) + (pos >> 1);
                const int ch = c * 32 + ko;
                aq1[c][j] = f2bf_trunc((x1f[c][j] - m1) * rstd1 * g1[ch] + be1[ch]);
            }

        f32x4 ACC[8];
        #pragma unroll
        for (int t = 0; t < 8; ++t) ACC[t] = zero;
        for (int i = 0; i < 8; ++i) {
            const int ffc = (wave << 3) + i;              // global 32-FF chunk [0,64)
            f32x4 p0 = zero, p1 = zero;
            #pragma unroll
            for (int c = 0; c < 4; ++c) {
                short8 b = *(const short8*)(W1f + ((size_t)(ffc * 8 + c) << 9) + lane * 8);
                p0 = mfma16(aq1[c], b, p0);
            }
            #pragma unroll
            for (int c = 0; c < 4; ++c) {
                short8 b = *(const short8*)(W1f + ((size_t)(ffc * 8 + 4 + c) << 9) + lane * 8);
                p1 = mfma16(aq1[c], b, p1);
            }
            const float bb0 = b1[ffc * 32 + col], bb1 = b1[ffc * 32 + 16 + col];
            unsigned int* Pw = &sh.mg.Pb[wave][i & 1][0];
            #pragma unroll
            for (int r = 0; r < 4; ++r)
                Pw[(quad * 4 + r) * 20 + col] =
                    pack_trunc(fmaxf(p0[r] + bb0, 0.f), fmaxf(p1[r] + bb1, 0.f));
            short8 ah = *(const short8*)((const short*)Pw + col * 40 + quad * 8);
            #pragma unroll
            for (int t = 0; t < 8; ++t) {
                short8 bw = *(const short8*)(W2f + ((size_t)(t * 64 + ffc) << 9) + lane * 8);
                ACC[t] = mfma16(ah, bw, ACC[t]);
            }
        }

        if (wave) {
            #pragma unroll
            for (int t = 0; t < 8; ++t)
                #pragma unroll
                for (int r = 0; r < 4; ++r)
                    sh.mg.comb[(wave - 1) * 32 + t * 4 + r][lane] = ACC[t][r];
        }
        __syncthreads();
        if (wave == 0) {
            #pragma unroll
            for (int t = 0; t < 8; ++t)
                #pragma unroll
                for (int r = 0; r < 4; ++r) {
                    float acc = ACC[t][r];
                    #pragma unroll
                    for (int w = 0; w < 7; ++w)
                        acc += sh.mg.comb[w * 32 + t * 4 + r][lane];
                    ACC[t][r] = acc;
                }
            short* xb = (short*)&sh.mg.Pb[0][0][0];   // [row16][chunk][32 pk] = 4096 shorts
            #pragma unroll
            for (int c = 0; c < 4; ++c)
                *(short8*)(xb + (col * 4 + c) * 32 + quad * 8) = aq1[c];
            float t2[8][4];
            #pragma unroll
            for (int t = 0; t < 8; ++t) {
                const int ch = t * 16 + col;
                const int pk = (col << 1) + (t & 1);
                const int c = t >> 1;
                const float bb = b2[ch];
                #pragma unroll
                for (int r = 0; r < 4; ++r)
                    t2[t][r] = ACC[t][r] + bb + bfs2f(xb[((quad * 4 + r) * 4 + c) * 32 + pk]);
            }
            #pragma unroll
            for (int r = 0; r < 4; ++r) {
                float S = 0.f, SS = 0.f;
                #pragma unroll
                for (int t = 0; t < 8; ++t) { S += t2[t][r]; SS += t2[t][r] * t2[t][r]; }
                S  += __shfl_xor(S, 1);  S  += __shfl_xor(S, 2);
                S  += __shfl_xor(S, 4);  S  += __shfl_xor(S, 8);
                SS += __shfl_xor(SS, 1); SS += __shfl_xor(SS, 2);
                SS += __shfl_xor(SS, 4); SS += __shfl_xor(SS, 8);
                const float m2 = S * (1.f / 128.f);
                const float rstd2 = rsqrtf(SS * (1.f / 128.f) - m2 * m2 + 1e-5f);
                #pragma unroll
                for (int t = 0; t < 8; ++t) {
                    const int ch = t * 16 + col;
                    out[(size_t)ch * N_ + n0 + quad * 4 + r] =
                        (t2[t][r] - m2) * rstd2 * g2[ch] + be2[ch];
                }
            }
        }
    }
}

extern "C" void kernel_launch(void* const* d_in, const int* in_sizes, int n_in,
                              void* d_out, int out_size, void* d_ws, size_t ws_size,
                              hipStream_t stream) {
    const float* x   = (const float*)d_in[0];
    const float* Wq  = (const float*)d_in[1];
    const float* bq  = (const float*)d_in[2];
    const float* Wk  = (const float*)d_in[3];
    const float* bk  = (const float*)d_in[4];
    const float* Wv  = (const float*)d_in[5];
    const float* bv  = (const float*)d_in[6];
    const float* Wo  = (const float*)d_in[7];
    const float* bo  = (const float*)d_in[8];
    const float* W1  = (const float*)d_in[9];
    const float* b1  = (const float*)d_in[10];
    const float* W2  = (const float*)d_in[11];
    const float* b2  = (const float*)d_in[12];
    const float* g1  = (const float*)d_in[13];
    const float* be1 = (const float*)d_in[14];
    const float* g2  = (const float*)d_in[15];
    const float* be2 = (const float*)d_in[16];
    float* out = (float*)d_out;

    char* ws = (char*)d_ws;
    bf16* xTf   = (bf16*)(ws + 0);          // 1 MB
    bf16* qf    = (bf16*)(ws + 1048576);    // 1 MB
    bf16* kf    = (bf16*)(ws + 2097152);    // 1 MB
    bf16* vf    = (bf16*)(ws + 3145728);    // 1 MB
    bf16* af    = (bf16*)(ws + 4194304);    // 1 MB
    bf16* Wqkvf = (bf16*)(ws + 5242880);    // 96 KB
    bf16* Wof   = (bf16*)(ws + 5341184);    // 32 KB
    bf16* W1f   = (bf16*)(ws + 5373952);    // 512 KB
    bf16* W2f   = (bf16*)(ws + 5898240);    // 512 KB
    unsigned int* bar = (unsigned int*)(ws + (8 << 20));   // barrier counter

    hipMemsetAsync(bar, 0, 256, stream);
    k_fused<<<256, 512, 0, stream>>>(x, Wq, Wk, Wv, Wo, W1, W2,
                                     bq, bk, bv, bo, b1, b2, g1, be1, g2, be2,
                                     xTf, Wqkvf, Wof, W1f, W2f, qf, kf, vf, af,
                                     out, bar);
}

// Round 5
// 145.894 us; speedup vs baseline: 1.4515x; 1.4515x over previous
//
#include <hip/hip_runtime.h>
#include <hip/hip_bf16.h>

typedef __hip_bfloat16 bf16;
typedef short short8 __attribute__((ext_vector_type(8)));
typedef float f32x4 __attribute__((ext_vector_type(4)));
typedef unsigned int u32x4 __attribute__((ext_vector_type(4)));

#define C_   128
#define N_   4096
#define NH_  8
#define HD_  16
#define FF_  2048
#define SCALE_Q 0.360673760222241f   // 0.25 * log2(e); attn uses v_exp_f32 (2^x)

__device__ __forceinline__ unsigned short f2bf_bits(float f) {
    bf16 h = __float2bfloat16(f);
    return *reinterpret_cast<unsigned short*>(&h);
}
// truncation-mode bf16 pack: single v_perm_b32. Bit-identical to (hi&0xffff0000)|(lo>>16).
__device__ __forceinline__ unsigned int pack_trunc(float lo, float hi) {
    return __builtin_amdgcn_perm(__float_as_uint(hi), __float_as_uint(lo), 0x07060302u);
}
__device__ __forceinline__ short f2bf_trunc(float f) {
    return (short)(__float_as_uint(f) >> 16);
}
__device__ __forceinline__ float bfs2f(short s) {
    return __uint_as_float(((unsigned int)(unsigned short)s) << 16);
}
__device__ __forceinline__ float fast_exp2(float x) {
    return __builtin_amdgcn_exp2f(x);
}
__device__ __forceinline__ f32x4 mfma16(short8 a, short8 b, f32x4 c) {
    return __builtin_amdgcn_mfma_f32_16x16x32_bf16(a, b, c, 0, 0, 0);
}

// ---------------- K0: prep — vectorized: one short8 (16B) store per thread ----------
__global__ void __launch_bounds__(256) k_prep(
    const float* __restrict__ Wq, const float* __restrict__ Wk,
    const float* __restrict__ Wv, const float* __restrict__ Wo,
    const float* __restrict__ W1, const float* __restrict__ W2,
    const float* __restrict__ x,
    bf16* __restrict__ Wqkvf, bf16* __restrict__ Wof,
    bf16* __restrict__ W1f, bf16* __restrict__ W2f,
    bf16* __restrict__ xTf)
{
    const int i = blockIdx.x * 256 + threadIdx.x;   // [0, 139264)
    if (i < 73728) {
        const float* row;
        bf16* dst;
        int kblk, g;
        if (i < 8192) {                      // QKV (o 0..383) + Wo (o 384..511), K=128
            const int o = i >> 4;
            kblk = (i >> 2) & 3; g = i & 3;
            const int odx = (o < 384) ? o : o - 384;
            row = (o < 128) ? (Wq + o * 128)
                : (o < 256) ? (Wk + (o - 128) * 128)
                : (o < 384) ? (Wv + (o - 256) * 128)
                            : (Wo + (o - 384) * 128);
            bf16* buf = (o < 384) ? Wqkvf : Wof;
            dst = buf + ((((odx >> 4) << 2) + kblk) * 512 + ((g << 4) + (odx & 15)) * 8);
        } else if (i < 40960) {              // W1 : [2048][128]
            const int t = i - 8192, o = t >> 4;
            kblk = (t >> 2) & 3; g = t & 3;
            row = W1 + o * 128;
            dst = W1f + ((((o >> 4) << 2) + kblk) * 512 + ((g << 4) + (o & 15)) * 8);
        } else {                             // W2 : [128][2048]
            const int t = i - 40960, o = t >> 8;
            kblk = (t >> 2) & 63; g = t & 3;
            row = W2 + o * 2048;
            dst = W2f + ((((o >> 4) << 6) + kblk) * 512 + ((g << 4) + (o & 15)) * 8);
        }
        const int k0 = kblk * 32 + g * 4;
        const f32x4 lo = *(const f32x4*)(row + k0);
        const f32x4 hi = *(const f32x4*)(row + k0 + 16);
        u32x4 w;
        #pragma unroll
        for (int j = 0; j < 4; ++j)
            w[j] = ((unsigned int)f2bf_bits(hi[j]) << 16) | f2bf_bits(lo[j]);
        *(u32x4*)dst = w;
    } else {                                 // x : [128][4096] -> xTf A-frags (transpose)
        const int t = i - 73728;             // [0, 65536)
        const int n = t & 4095, g = (t >> 12) & 3, cblk = t >> 14;
        const int c0 = cblk * 32 + g * 4;
        const float* xs = x + (size_t)c0 * 4096 + n;
        u32x4 w;
        #pragma unroll
        for (int j = 0; j < 4; ++j)
            w[j] = ((unsigned int)f2bf_bits(xs[(size_t)(16 + j) * 4096]) << 16)
                 | f2bf_bits(xs[(size_t)j * 4096]);
        bf16* dst = xTf + ((((n >> 4) << 2) + cblk) * 512 + ((g << 4) + (n & 15)) * 8);
        *(u32x4*)dst = w;
    }
}

// ---------------- K1: QKV — barrier-free fragment-streaming GEMM ----------------
__global__ void __launch_bounds__(256) k_qkv(
    const bf16* __restrict__ xTf, const bf16* __restrict__ Wqkvf,
    const float* __restrict__ bq, const float* __restrict__ bk, const float* __restrict__ bv,
    bf16* __restrict__ qf, bf16* __restrict__ kf, bf16* __restrict__ vf)
{
    const int tid = threadIdx.x, wave = tid >> 6, lane = tid & 63;
    const int col = lane & 15, quad = lane >> 4;
    const int gw = blockIdx.x * 4 + wave;     // [0, 6144)
    const int rt = gw / 24, ct = gw % 24;
    f32x4 acc = {};
    #pragma unroll
    for (int c = 0; c < 4; ++c) {
        short8 a = *(const short8*)(xTf + ((size_t)(rt * 4 + c) << 9) + lane * 8);
        short8 b = *(const short8*)(Wqkvf + ((size_t)(ct * 4 + c) << 9) + lane * 8);
        acc = mfma16(a, b, acc);
    }
    #pragma unroll
    for (int r = 0; r < 4; ++r) {
        const int m = rt * 16 + quad * 4 + r;
        const int n = ct * 16 + col;
        const float v = acc[r];
        if (n < 128) {
            const int h = n >> 4, ch = n & 15;
            qf[((h << 8) + (m >> 4)) * 256 + (((ch >> 3) << 4) + (m & 15)) * 8 + (ch & 7)] =
                __float2bfloat16((v + bq[n]) * SCALE_Q);
        } else if (n < 256) {
            const int c2 = n - 128, h = c2 >> 4, ch = c2 & 15;
            kf[((h << 8) + (m >> 4)) * 256 + (((ch >> 3) << 4) + (m & 15)) * 8 + (ch & 7)] =
                __float2bfloat16(v + bk[c2]);
        } else {
            const int c2 = n - 256, h = c2 >> 4, ch = c2 & 15;
            const int ko = m & 31;
            const int pos = ((ko & 15) << 1) + (ko >> 4);
            vf[((h << 7) + (m >> 5)) * 512 + (((pos >> 3) << 4) + ch) * 8 + (pos & 7)] =
                __float2bfloat16(v + bv[c2]);
        }
    }
}

// ---------------- K2: MFMA flash attention — q-tile grouping for KV L2 reuse (R14) ------
__global__ void __launch_bounds__(256)
attn_kernel(const bf16* __restrict__ qf, const bf16* __restrict__ kf,
            const bf16* __restrict__ vf, bf16* __restrict__ af)
{
    __shared__ __align__(16) union {
        unsigned int P[4][4][2][320];   // [wave][qt][buf] transpose bufs, 40 KB
        float comb[4][4][64][8];        // [qt][wave][lane][O0..3,L0..3], 32 KB
    } sh;
    const int tid = threadIdx.x, wave = tid >> 6, lane = tid & 63;
    const int col = lane & 15, quad = lane >> 4;
    const int gw = blockIdx.x;                   // [0, 512)
    const int h  = gw >> 6;
    const int tile0 = (gw & 63) << 2;
    const f32x4 zero = {};

    short8 aq[4] = {{}, {}, {}, {}};
    if (quad < 2) {
        #pragma unroll
        for (int qt = 0; qt < 4; ++qt)
            aq[qt] = *(const short8*)(qf + ((size_t)((h << 8) + tile0 + qt) << 8) + lane * 8);
    }

    const short8 onesb = { (short)0x3F80, (short)0x3F80, (short)0x3F80, (short)0x3F80,
                           (short)0x3F80, (short)0x3F80, (short)0x3F80, (short)0x3F80 };

    f32x4 accO[4] = {{}, {}, {}, {}};
    f32x4 accL[4] = {{}, {}, {}, {}};

    const int kbeg = wave << 10;

    for (int i = 0; i < 32; i += 2) {
        const int mA = kbeg + (i << 5);
        const int mB = mA + 32;

        short8 bkA0 = {}, bkA1 = {}, bkB0 = {}, bkB1 = {};
        if (quad < 2) {
            const bf16* ka = kf + ((size_t)((h << 8) + (mA >> 4)) << 8) + lane * 8;
            bkA0 = *(const short8*)(ka);
            bkA1 = *(const short8*)(ka + 256);
            bkB0 = *(const short8*)(ka + 512);
            bkB1 = *(const short8*)(ka + 768);
        }
        const short8 vA = *(const short8*)(vf + ((size_t)((h << 7) + (mA >> 5)) << 9) + lane * 8);
        const short8 vB = *(const short8*)(vf + ((size_t)((h << 7) + (mB >> 5)) << 9) + lane * 8);

        #pragma unroll
        for (int qt = 0; qt < 4; ++qt) {
            f32x4 s0 = mfma16(aq[qt], bkA0, zero);
            f32x4 s1 = mfma16(aq[qt], bkA1, zero);
            f32x4 s2 = mfma16(aq[qt], bkB0, zero);
            f32x4 s3 = mfma16(aq[qt], bkB1, zero);
            unsigned int* P0 = &sh.P[wave][qt][0][0];
            unsigned int* P1 = &sh.P[wave][qt][1][0];
            #pragma unroll
            for (int r = 0; r < 4; ++r) {
                P0[(quad * 4 + r) * 20 + col] = pack_trunc(fast_exp2(s0[r]), fast_exp2(s1[r]));
                P1[(quad * 4 + r) * 20 + col] = pack_trunc(fast_exp2(s2[r]), fast_exp2(s3[r]));
            }
        }
        #pragma unroll
        for (int qt = 0; qt < 4; ++qt) {
            const short* Ps0 = (const short*)&sh.P[wave][qt][0][0];
            const short* Ps1 = (const short*)&sh.P[wave][qt][1][0];
            short8 ap0 = *(const short8*)(Ps0 + col * 40 + quad * 8);
            accO[qt] = mfma16(ap0, vA, accO[qt]);
            accL[qt] = mfma16(ap0, onesb, accL[qt]);
            short8 ap1 = *(const short8*)(Ps1 + col * 40 + quad * 8);
            accO[qt] = mfma16(ap1, vB, accO[qt]);
            accL[qt] = mfma16(ap1, onesb, accL[qt]);
        }
    }

    __syncthreads();
    #pragma unroll
    for (int qt = 0; qt < 4; ++qt)
        #pragma unroll
        for (int r = 0; r < 4; ++r) {
            sh.comb[qt][wave][lane][r]     = accO[qt][r];
            sh.comb[qt][wave][lane][4 + r] = accL[qt][r];
        }
    __syncthreads();

    {   // wave w finalizes q-tile w
        const int qt = wave, tile = tile0 + qt;
        #pragma unroll
        for (int r = 0; r < 4; ++r) {
            float O = sh.comb[qt][0][lane][r] + sh.comb[qt][1][lane][r]
                    + sh.comb[qt][2][lane][r] + sh.comb[qt][3][lane][r];
            float l = sh.comb[qt][0][lane][4+r] + sh.comb[qt][1][lane][4+r]
                    + sh.comb[qt][2][lane][4+r] + sh.comb[qt][3][lane][4+r];
            const int row16 = quad * 4 + r;
            const int pk = (col << 1) + (h & 1);
            af[((tile << 2) + (h >> 1)) * 512 + (((pk >> 3) << 4) + row16) * 8 + (pk & 7)] =
                __float2bfloat16(O / l);
        }
    }
}

// ---------------- K3a: oproj + residual + LN1 -> x1 normalized A-frags ------------------
// R16: mega split. 256 blocks x 4 waves; all 4 waves redundantly compute the block's
// 16-row tile (oproj 32 MFMA is cheap); wave0 stores aq1 frags to x1qf.
__global__ void __launch_bounds__(256)
k_ln1(const bf16* __restrict__ af, const bf16* __restrict__ xTf,
      const bf16* __restrict__ Wof, const float* __restrict__ bo,
      const float* __restrict__ g1, const float* __restrict__ be1,
      bf16* __restrict__ x1qf)
{
    __shared__ __align__(16) unsigned int Pb[4][2][320];
    const int tid = threadIdx.x, wave = tid >> 6, lane = tid & 63;
    const int col = lane & 15, quad = lane >> 4;
    const int rt = blockIdx.x;
    const f32x4 zero = {};

    short8 ao[4], xt[4];
    #pragma unroll
    for (int c = 0; c < 4; ++c) {
        ao[c] = *(const short8*)(af  + ((size_t)(rt * 4 + c) << 9) + lane * 8);
        xt[c] = *(const short8*)(xTf + ((size_t)(rt * 4 + c) << 9) + lane * 8);
    }
    f32x4 d[8];
    #pragma unroll
    for (int t = 0; t < 8; ++t) d[t] = zero;
    #pragma unroll
    for (int t = 0; t < 8; ++t)
        #pragma unroll
        for (int c = 0; c < 4; ++c) {
            short8 b = *(const short8*)(Wof + ((size_t)(t * 4 + c) << 9) + lane * 8);
            d[t] = mfma16(ao[c], b, d[t]);
        }
    #pragma unroll
    for (int t = 0; t < 8; ++t) {
        const float bt = bo[t * 16 + col];
        #pragma unroll
        for (int r = 0; r < 4; ++r) d[t][r] += bt;
    }

    float x1f[4][8];
    #pragma unroll
    for (int c = 0; c < 4; ++c) {
        unsigned int* Pw = &Pb[wave][c & 1][0];
        const short* Ps = (const short*)Pw;
        #pragma unroll
        for (int r = 0; r < 4; ++r)
            Pw[(quad * 4 + r) * 20 + col] = pack_trunc(d[2 * c][r], d[2 * c + 1][r]);
        short8 ar = *(const short8*)(Ps + col * 40 + quad * 8);
        #pragma unroll
        for (int j = 0; j < 8; ++j)
            x1f[c][j] = bfs2f(ar[j]) + bfs2f(xt[c][j]);
    }

    float s = 0.f, ss = 0.f;
    #pragma unroll
    for (int c = 0; c < 4; ++c)
        #pragma unroll
        for (int j = 0; j < 8; ++j) { s += x1f[c][j]; ss += x1f[c][j] * x1f[c][j]; }
    s  += __shfl_xor(s, 16);  s  += __shfl_xor(s, 32);
    ss += __shfl_xor(ss, 16); ss += __shfl_xor(ss, 32);
    const float m1 = s * (1.f / 128.f);
    const float rstd1 = rsqrtf(ss * (1.f / 128.f) - m1 * m1 + 1e-5f);
    #pragma unroll
    for (int c = 0; c < 4; ++c) {
        short8 aq1;
        #pragma unroll
        for (int j = 0; j < 8; ++j) {
            const int pos = quad * 8 + j;
            const int ko = ((pos & 1) << 4) + (pos >> 1);
            const int ch = c * 32 + ko;
            aq1[j] = f2bf_trunc((x1f[c][j] - m1) * rstd1 * g1[ch] + be1[ch]);
        }
        if (wave == 0)
            *(short8*)((short*)x1qf + ((size_t)(rt * 4 + c) << 9) + lane * 8) = aq1;
    }
}

// ---------------- K3b: FFN1+FFN2 split-K over 8 FF-eighths (XCD-aligned) ----------------
// 512 blocks x 8 waves, 2 blocks/CU. fq = blk & 7 -> all blocks of one FF-eighth land on
// one XCD (blk%8 = XCD), so each XCD's L2 holds only its 256 KB weight slice (vs 1 MB x
// all CUs before; aggregate L2 reads 256->64 MB). Block: 64 rows (4 rt) x 256 FF
// (8 chunks). wave -> (rt = w&3, chunk-half = w>>2). fq0 adds b2 + residual x1n.
// f32 partials to ws; summed in k_fin (reassociation only vs R14).
__global__ void __launch_bounds__(512, 4)
k_ffn(const bf16* __restrict__ x1qf, const bf16* __restrict__ W1f,
      const bf16* __restrict__ W2f, const float* __restrict__ b1,
      const float* __restrict__ b2, float* __restrict__ partial)
{
    __shared__ __align__(16) unsigned int Pb[8][2][320];   // 20 KB
    __shared__ float comb[4][32][64];                       // 32 KB
    __shared__ short xb[4][2048];                           // 16 KB (fq0 residual recovery)
    const int tid = threadIdx.x, wave = tid >> 6, lane = tid & 63;
    const int col = lane & 15, quad = lane >> 4;
    const int blk = blockIdx.x;
    const int fq = blk & 7, nt = blk >> 3;                  // fq = XCD id
    const int rt_l = wave & 3, chalf = wave >> 2;
    const int grt = nt * 4 + rt_l, n0 = grt << 4;
    const f32x4 zero = {};

    short8 aq1[4];
    #pragma unroll
    for (int c = 0; c < 4; ++c)
        aq1[c] = *(const short8*)((const short*)x1qf + ((size_t)(grt * 4 + c) << 9) + lane * 8);

    f32x4 ACC[8];
    #pragma unroll
    for (int t = 0; t < 8; ++t) ACC[t] = zero;
    #pragma unroll
    for (int i = 0; i < 4; ++i) {
        const int ffc = fq * 8 + chalf * 4 + i;             // global 32-FF chunk [0,64)
        f32x4 p0 = zero, p1 = zero;
        #pragma unroll
        for (int c = 0; c < 4; ++c) {
            short8 b = *(const short8*)(W1f + ((size_t)(ffc * 8 + c) << 9) + lane * 8);
            p0 = mfma16(aq1[c], b, p0);
        }
        #pragma unroll
        for (int c = 0; c < 4; ++c) {
            short8 b = *(const short8*)(W1f + ((size_t)(ffc * 8 + 4 + c) << 9) + lane * 8);
            p1 = mfma16(aq1[c], b, p1);
        }
        const float bb0 = b1[ffc * 32 + col], bb1 = b1[ffc * 32 + 16 + col];
        unsigned int* Pw = &Pb[wave][i & 1][0];
        #pragma unroll
        for (int r = 0; r < 4; ++r)
            Pw[(quad * 4 + r) * 20 + col] =
                pack_trunc(fmaxf(p0[r] + bb0, 0.f), fmaxf(p1[r] + bb1, 0.f));
        short8 ah = *(const short8*)((const short*)Pw + col * 40 + quad * 8);
        #pragma unroll
        for (int t = 0; t < 8; ++t) {
            short8 bw = *(const short8*)(W2f + ((size_t)(t * 64 + ffc) << 9) + lane * 8);
            ACC[t] = mfma16(ah, bw, ACC[t]);
        }
    }

    if (wave >= 4) {
        #pragma unroll
        for (int t = 0; t < 8; ++t)
            #pragma unroll
            for (int r = 0; r < 4; ++r)
                comb[wave - 4][t * 4 + r][lane] = ACC[t][r];
    }
    __syncthreads();
    if (wave < 4) {
        #pragma unroll
        for (int t = 0; t < 8; ++t)
            #pragma unroll
            for (int r = 0; r < 4; ++r)
                ACC[t][r] += comb[wave][t * 4 + r][lane];

        float* pdst = partial + ((size_t)fq << 19);         // fq * 4096 * 128
        if (fq == 0) {
            short* x = &xb[wave][0];                        // [row16][c4][32 pk]
            #pragma unroll
            for (int c = 0; c < 4; ++c)
                *(short8*)(x + (col * 4 + c) * 32 + quad * 8) = aq1[c];
            #pragma unroll
            for (int t = 0; t < 8; ++t) {
                const int ch = t * 16 + col;
                const int pk = (col << 1) + (t & 1);
                const int c = t >> 1;
                const float bb = b2[ch];
                #pragma unroll
                for (int r = 0; r < 4; ++r)
                    pdst[(size_t)(n0 + quad * 4 + r) * 128 + ch] =
                        ACC[t][r] + bb + bfs2f(x[((quad * 4 + r) * 4 + c) * 32 + pk]);
            }
        } else {
            #pragma unroll
            for (int t = 0; t < 8; ++t) {
                const int ch = t * 16 + col;
                #pragma unroll
                for (int r = 0; r < 4; ++r)
                    pdst[(size_t)(n0 + quad * 4 + r) * 128 + ch] = ACC[t][r];
            }
        }
    }
}

// ---------------- K3c: combine 8 partials + LN2 + transposed store ----------------------
__global__ void __launch_bounds__(512)
k_fin(const float* __restrict__ partial, const float* __restrict__ g2,
      const float* __restrict__ be2, float* __restrict__ out)
{
    const int tid = threadIdx.x;
    const int cq = tid & 31, ri = tid >> 5;                 // 32 c-quads x 16 rows
    const int n = blockIdx.x * 16 + ri;

    const float* ps = partial + (size_t)n * 128 + cq * 4;
    f32x4 v = {};
    #pragma unroll
    for (int fq = 0; fq < 8; ++fq) {
        const f32x4 p = *(const f32x4*)(ps + ((size_t)fq << 19));
        #pragma unroll
        for (int k = 0; k < 4; ++k) v[k] += p[k];
    }
    float S = 0.f, SS = 0.f;
    #pragma unroll
    for (int k = 0; k < 4; ++k) { S += v[k]; SS += v[k] * v[k]; }
    S  += __shfl_xor(S, 1);  S  += __shfl_xor(S, 2);
    S  += __shfl_xor(S, 4);  S  += __shfl_xor(S, 8);  S  += __shfl_xor(S, 16);
    SS += __shfl_xor(SS, 1); SS += __shfl_xor(SS, 2);
    SS += __shfl_xor(SS, 4); SS += __shfl_xor(SS, 8); SS += __shfl_xor(SS, 16);
    const float m2 = S * (1.f / 128.f);
    const float rstd2 = rsqrtf(SS * (1.f / 128.f) - m2 * m2 + 1e-5f);
    #pragma unroll
    for (int k = 0; k < 4; ++k) {
        const int ch = cq * 4 + k;
        out[(size_t)ch * N_ + n] = (v[k] - m2) * rstd2 * g2[ch] + be2[ch];
    }
}

extern "C" void kernel_launch(void* const* d_in, const int* in_sizes, int n_in,
                              void* d_out, int out_size, void* d_ws, size_t ws_size,
                              hipStream_t stream) {
    const float* x   = (const float*)d_in[0];
    const float* Wq  = (const float*)d_in[1];
    const float* bq  = (const float*)d_in[2];
    const float* Wk  = (const float*)d_in[3];
    const float* bk  = (const float*)d_in[4];
    const float* Wv  = (const float*)d_in[5];
    const float* bv  = (const float*)d_in[6];
    const float* Wo  = (const float*)d_in[7];
    const float* bo  = (const float*)d_in[8];
    const float* W1  = (const float*)d_in[9];
    const float* b1  = (const float*)d_in[10];
    const float* W2  = (const float*)d_in[11];
    const float* b2  = (const float*)d_in[12];
    const float* g1  = (const float*)d_in[13];
    const float* be1 = (const float*)d_in[14];
    const float* g2  = (const float*)d_in[15];
    const float* be2 = (const float*)d_in[16];
    float* out = (float*)d_out;

    char* ws = (char*)d_ws;
    bf16* xTf   = (bf16*)(ws + 0);          // 1 MB
    bf16* qf    = (bf16*)(ws + 1048576);    // 1 MB
    bf16* kf    = (bf16*)(ws + 2097152);    // 1 MB
    bf16* vf    = (bf16*)(ws + 3145728);    // 1 MB
    bf16* af    = (bf16*)(ws + 4194304);    // 1 MB
    bf16* Wqkvf = (bf16*)(ws + 5242880);    // 96 KB
    bf16* Wof   = (bf16*)(ws + 5341184);    // 32 KB
    bf16* W1f   = (bf16*)(ws + 5373952);    // 512 KB
    bf16* W2f   = (bf16*)(ws + 5898240);    // 512 KB
    bf16* x1qf  = (bf16*)(ws + 6422528);    // 1 MB  (LN1-normalized x1 A-frags)
    float* partial = (float*)(ws + 7471104); // 8 x 2 MB f32 ffn partials (16 MB)

    k_prep<<<544, 256, 0, stream>>>(Wq, Wk, Wv, Wo, W1, W2, x, Wqkvf, Wof, W1f, W2f, xTf);
    k_qkv<<<1536, 256, 0, stream>>>(xTf, Wqkvf, bq, bk, bv, qf, kf, vf);
    attn_kernel<<<512, 256, 0, stream>>>(qf, kf, vf, af);
    k_ln1<<<256, 256, 0, stream>>>(af, xTf, Wof, bo, g1, be1, x1qf);
    k_ffn<<<512, 512, 0, stream>>>(x1qf, W1f, W2f, b1, b2, partial);
    k_fin<<<256, 512, 0, stream>>>(partial, g2, be2, out);
}